// Round 2
// baseline (401.502 us; speedup 1.0000x reference)
//
#include <hip/hip_runtime.h>
#include <hip/hip_bf16.h>

#define NN 2048
#define BB 8
#define TROW 128928   // sum_{d=1..64} (2047-d)

// ---------------- k_left: R[b][i][k] = dot(x[b,i,:], wl[k,:]), k=(c*3+dh) in [0,15) ----------
// grid 1024 = 8 b x 128 rowgroups(16 rows); block 256 = 4 waves; wave handles 4 rows.
__global__ __launch_bounds__(256) void k_left(const float* __restrict__ x,
                                              const float* __restrict__ wl,
                                              float* __restrict__ R) {
    __shared__ float red[4][60 * 65];
    int b = blockIdx.x >> 7;
    int rbase = (blockIdx.x & 127) << 4;
    int wv = threadIdx.x >> 6, lane = threadIdx.x & 63;
    int r0 = rbase + wv * 4;
    const float* xp = x + ((size_t)(b * NN + r0)) * NN;

    float acc[4][15];
#pragma unroll
    for (int r = 0; r < 4; r++)
#pragma unroll
        for (int k = 0; k < 15; k++) acc[r][k] = 0.f;

    for (int seg = 0; seg < 8; seg++) {
        int j0 = seg * 256 + lane * 4;
        float4 xv[4];
#pragma unroll
        for (int r = 0; r < 4; r++) xv[r] = *(const float4*)(xp + (size_t)r * NN + j0);
#pragma unroll
        for (int k = 0; k < 15; k++) {
            float4 w4 = *(const float4*)(wl + (size_t)k * NN + j0);
#pragma unroll
            for (int r = 0; r < 4; r++) {
                acc[r][k] = fmaf(xv[r].x, w4.x, acc[r][k]);
                acc[r][k] = fmaf(xv[r].y, w4.y, acc[r][k]);
                acc[r][k] = fmaf(xv[r].z, w4.z, acc[r][k]);
                acc[r][k] = fmaf(xv[r].w, w4.w, acc[r][k]);
            }
        }
    }
#pragma unroll
    for (int r = 0; r < 4; r++)
#pragma unroll
        for (int k = 0; k < 15; k++) red[wv][(r * 15 + k) * 65 + lane] = acc[r][k];
    __syncthreads();
    if (lane < 60) {
        const float* rp = &red[wv][lane * 65];
        float s = 0.f;
#pragma unroll
        for (int j = 0; j < 64; j++) s += rp[j];
        int r = lane / 15, k = lane - r * 15;
        R[(size_t)(b * NN + r0 + r) * 16 + k] = s;
    }
}

// ---------------- k_right: CS[b][k][j] += sum_h x[b,h,j]*wr[c,h,dw], k=(c*3+dw) --------------
// grid 512 = 8 b x 2 col-halves x 32 rowchunks(64 rows); block 256; thread owns 4 cols.
__global__ __launch_bounds__(256) void k_right(const float* __restrict__ x,
                                               const float* __restrict__ wr,
                                               float* __restrict__ CS) {
    __shared__ float wf[64][16];
    int b = blockIdx.x >> 6;
    int rem = blockIdx.x & 63;
    int half = rem >> 5, rc = rem & 31;
    int h0 = rc * 64;
    int tid = threadIdx.x;
    for (int idx = tid; idx < 64 * 15; idx += 256) {
        int hh = idx / 15, k = idx - hh * 15;
        int c = k / 3, dw = k - c * 3;
        wf[hh][k] = wr[c * (NN * 3) + (h0 + hh) * 3 + dw];
    }
    __syncthreads();
    int j0 = half * 1024 + tid * 4;
    const float* xp = x + ((size_t)b * NN + h0) * NN + j0;
    float acc[15][4];
#pragma unroll
    for (int k = 0; k < 15; k++)
#pragma unroll
        for (int e = 0; e < 4; e++) acc[k][e] = 0.f;

    for (int hh = 0; hh < 64; hh++) {
        float4 xv = *(const float4*)(xp + (size_t)hh * NN);
        float xf[4] = {xv.x, xv.y, xv.z, xv.w};
#pragma unroll
        for (int k = 0; k < 15; k++) {
            float w = wf[hh][k];
#pragma unroll
            for (int e = 0; e < 4; e++) acc[k][e] = fmaf(xf[e], w, acc[k][e]);
        }
    }
    float* csb = CS + (size_t)b * 16 * NN;
#pragma unroll
    for (int k = 0; k < 15; k++)
#pragma unroll
        for (int e = 0; e < 4; e++) atomicAdd(&csb[k * NN + j0 + e], acc[k][e]);
}

// ---------------- k_combine: lr[b][ch][i] (ch<5: left_+bl shifts of R; ch>=5: right_+br of CS)
__global__ __launch_bounds__(256) void k_combine(const float* __restrict__ R,
                                                 const float* __restrict__ CS,
                                                 const float* __restrict__ bl,
                                                 const float* __restrict__ br,
                                                 float* __restrict__ LR) {
    int t = blockIdx.x * 256 + threadIdx.x;
    if (t >= BB * 10 * NN) return;
    int b = t / (10 * NN);
    int rem = t - b * (10 * NN);
    int ch = rem >> 11;
    int i = rem & (NN - 1);
    float v;
    if (ch < 5) {
        v = bl[ch];
#pragma unroll
        for (int dh = 0; dh < 3; dh++) {
            int r = i + dh - 1;
            if (r >= 0 && r < NN) v += R[(size_t)(b * NN + r) * 16 + ch * 3 + dh];
        }
    } else {
        int c = ch - 5;
        v = br[c];
#pragma unroll
        for (int dw = 0; dw < 3; dw++) {
            int j = i + dw - 1;
            if (j >= 0 && j < NN) v += CS[((size_t)b * 16 + c * 3 + dw) * NN + j];
        }
    }
    LR[t] = v;
}

// ---------------- k_chain: 6 conv1d(k=3,pad=1)+relu layers + 1x1 sigmoid head ----------------
// grid 128 = 8 b x 16 chunks(128 cols); halo 6 each side -> ext 140 positions.
__global__ __launch_bounds__(256) void k_chain(const float* __restrict__ LR,
                                               const float* __restrict__ wA, const float* __restrict__ bA,
                                               const float* __restrict__ wB, const float* __restrict__ bB,
                                               const float* __restrict__ wT, const float* __restrict__ bT,
                                               const float* __restrict__ wm, const float* __restrict__ bm,
                                               float* __restrict__ LEFT, float* __restrict__ RIGHT) {
    __shared__ float buf0[10][144], buf1[10][144];
    __shared__ float W[3][10][10][3];
    __shared__ float Bs[3][10];
    __shared__ float Wm[2][10], Bm[2];
    int b = blockIdx.x >> 4;
    int c0 = (blockIdx.x & 15) << 7;
    int tid = threadIdx.x;

    for (int idx = tid; idx < 900; idx += 256) {
        int set = idx / 300, rem = idx - set * 300;
        int o = rem / 30, rem2 = rem - o * 30, c = rem2 / 3, kk = rem2 - c * 3;
        float u;
        if (set == 0) u = wA[o * 30 + c * 3 + kk];
        else if (set == 1) u = wB[o * 30 + c * 3 + kk];
        else u = wT[c * 30 + o * 3 + (2 - kk)];   // wTc[o,c,k] = wT[c,o,2-k]
        W[set][o][c][kk] = u;
    }
    if (tid < 30) {
        float v = (tid < 10) ? bA[tid] : (tid < 20) ? bB[tid - 10] : bT[tid - 20];
        Bs[tid / 10][tid % 10] = v;
    }
    if (tid < 20) Wm[tid / 10][tid % 10] = wm[tid];
    if (tid < 2) Bm[tid] = bm[tid];

    for (int idx = tid; idx < 1400; idx += 256) {
        int ch = idx / 140, p = idx - ch * 140;
        int g = c0 - 6 + p;
        buf0[ch][p] = (g >= 0 && g < NN) ? LR[((size_t)b * 10 + ch) * NN + g] : 0.f;
    }
    __syncthreads();

    float(*in)[144] = buf0;
    float(*out)[144] = buf1;
    for (int layer = 0; layer < 6; layer++) {
        int set = (layer == 0) ? 0 : (layer < 3 ? 1 : 2);
        int lo = layer + 1;  // valid p range [lo, 140-lo)
        for (int idx = tid; idx < 1400; idx += 256) {
            int o = idx / 140, p = idx - o * 140;
            if (p >= lo && p < 140 - lo) {
                float s = Bs[set][o];
#pragma unroll
                for (int c = 0; c < 10; c++) {
                    const float* ip = &in[c][p];
                    s = fmaf(ip[-1], W[set][o][c][0], s);
                    s = fmaf(ip[0], W[set][o][c][1], s);
                    s = fmaf(ip[1], W[set][o][c][2], s);
                }
                s = s > 0.f ? s : 0.f;
                int g = c0 - 6 + p;
                if (g < 0 || g >= NN) s = 0.f;  // reproduce zero padding at global edges
                out[o][p] = s;
            }
        }
        __syncthreads();
        float(*tmp)[144] = in; in = out; out = tmp;
    }
    // 1x1 conv to 2ch + sigmoid; write the 128 owned cols
    {
        int idx = tid;  // 256 = 2 ch x 128 cols
        int o = idx >> 7, pp = idx & 127;
        int p = 6 + pp;
        float s = Bm[o];
#pragma unroll
        for (int c = 0; c < 10; c++) s = fmaf(in[c][p], Wm[o][c], s);
        float sig = 1.f / (1.f + __expf(-s));
        (o ? RIGHT : LEFT)[b * NN + c0 + pp] = sig;
    }
}

// ---------------- k_diag: CUR[d-1][b][i] = exp(x[b,i,i+d]), d in [1,64] ----------------------
// grid 256 = 8 b x 32 rowtiles(64); block 256; LDS transpose for coalesced d-major writes.
__global__ __launch_bounds__(256) void k_diag(const float* __restrict__ x,
                                              float* __restrict__ CUR) {
    __shared__ float T[64][65];
    int b = blockIdx.x >> 5;
    int i0 = (blockIdx.x & 31) << 6;
    int tid = threadIdx.x;
    int rsub = tid >> 3, chunk = tid & 7;
#pragma unroll
    for (int rh = 0; rh < 2; rh++) {
        int rr = rsub + rh * 32;
        int row = i0 + rr;
        const float* xp = x + ((size_t)b * NN + row) * NN;
#pragma unroll
        for (int j = 0; j < 8; j++) {
            int d = chunk * 8 + j + 1;
            int col = row + d;
            float v = 0.f;
            if (col < NN) v = __expf(xp[col]);
            T[rr][d - 1] = v;
        }
    }
    __syncthreads();
    int lane = tid & 63, dgrp = tid >> 6;
#pragma unroll
    for (int sub = 0; sub < 16; sub++) {
        int dm1 = dgrp * 16 + sub;
        CUR[((size_t)dm1 * BB + b) * NN + i0 + lane] = T[lane][dm1];
    }
}

// ---------------- k_final: p = log(mass_in/mass_out) - global_mean(p); f32 out ---------------
// grid 64 (one block per d); block 1024.
__global__ __launch_bounds__(1024) void k_final(const float* __restrict__ CUR,
                                                const float* __restrict__ LEFT,
                                                const float* __restrict__ RIGHT,
                                                float* __restrict__ outp) {
    __shared__ float wsum[16];
    int dm1 = blockIdx.x;
    int d = dm1 + 1;
    int L = (NN - 1) - d;  // n - d - 1
    int tid = threadIdx.x;
    float pv[8][2];
    float lsum = 0.f;
#pragma unroll
    for (int b = 0; b < 8; b++) {
        const float* cur = CUR + ((size_t)dm1 * BB + b) * NN;
        const float* lf = LEFT + b * NN;
        const float* rt = RIGHT + b * NN;
#pragma unroll
        for (int it = 0; it < 2; it++) {
            int i = tid + it * 1024;
            float p = 0.f;
            if (i < L) {
                float ci = cur[i], ci1 = cur[i + 1];
                float mi = ci1 * rt[i + 1] + ci * lf[d + i];
                float mo = rt[i] + lf[d + 1 + i];
                p = __logf(mi / mo);
                lsum += p;
            }
            pv[b][it] = p;
        }
    }
    for (int off = 32; off; off >>= 1) lsum += __shfl_down(lsum, off);
    int lane = tid & 63, wv = tid >> 6;
    if (lane == 0) wsum[wv] = lsum;
    __syncthreads();
    if (wv == 0) {
        float s = (lane < 16) ? wsum[lane] : 0.f;
        for (int off = 8; off; off >>= 1) s += __shfl_down(s, off);
        if (lane == 0) wsum[0] = s;
    }
    __syncthreads();
    float mean = wsum[0] / (float)(8 * L);
    size_t off0 = (size_t)dm1 * (NN - 1) - (size_t)dm1 * (dm1 + 1) / 2;
#pragma unroll
    for (int b = 0; b < 8; b++) {
#pragma unroll
        for (int it = 0; it < 2; it++) {
            int i = tid + it * 1024;
            if (i < L) outp[(size_t)b * TROW + off0 + i] = pv[b][it] - mean;
        }
    }
}

extern "C" void kernel_launch(void* const* d_in, const int* in_sizes, int n_in,
                              void* d_out, int out_size, void* d_ws, size_t ws_size,
                              hipStream_t stream) {
    const float* x = (const float*)d_in[0];
    const float* wl = (const float*)d_in[1];
    const float* bl = (const float*)d_in[2];
    const float* wr = (const float*)d_in[3];
    const float* br = (const float*)d_in[4];
    const float* wA = (const float*)d_in[5];
    const float* bA = (const float*)d_in[6];
    const float* wB = (const float*)d_in[7];
    const float* bB = (const float*)d_in[8];
    const float* wT = (const float*)d_in[9];
    const float* bT = (const float*)d_in[10];
    const float* wm = (const float*)d_in[11];
    const float* bm = (const float*)d_in[12];
    // start/stop (d_in[13], d_in[14]) are fixed at 1/65 for this problem.

    float* ws = (float*)d_ws;
    float* R = ws;                  // 8*2048*16      = 262144 f
    float* CS = ws + 262144;        // 8*16*2048      = 262144 f
    float* LR = ws + 524288;        // 8*10*2048      = 163840 f
    float* LEFT = ws + 688128;      // 8*2048         = 16384 f
    float* RIGHT = ws + 704512;     // 8*2048         = 16384 f
    float* CUR = ws + 720896;       // 64*8*2048      = 1048576 f
    // total 1769472 floats = ~7.08 MB

    hipMemsetAsync(CS, 0, 262144 * sizeof(float), stream);
    k_left<<<1024, 256, 0, stream>>>(x, wl, R);
    k_right<<<512, 256, 0, stream>>>(x, wr, CS);
    k_combine<<<640, 256, 0, stream>>>(R, CS, bl, br, LR);
    k_chain<<<128, 256, 0, stream>>>(LR, wA, bA, wB, bB, wT, bT, wm, bm, LEFT, RIGHT);
    k_diag<<<256, 256, 0, stream>>>(x, CUR);
    k_final<<<64, 1024, 0, stream>>>(CUR, LEFT, RIGHT, (float*)d_out);
}

// Round 3
// 335.839 us; speedup vs baseline: 1.1955x; 1.1955x over previous
//
#include <hip/hip_runtime.h>
#include <hip/hip_bf16.h>

#define NN 2048
#define BB 8
#define TROW 128928   // sum_{d=1..64} (2047-d)

// ---------------- k_left: R[b][i][k] = dot(x[b,i,:], wl[k,:]), k=(c*3+dh) in [0,15) ----------
// grid 1024 = 8 b x 128 rowgroups(16 rows); block 256 = 4 waves; wave handles 4 rows.
__global__ __launch_bounds__(256) void k_left(const float* __restrict__ x,
                                              const float* __restrict__ wl,
                                              float* __restrict__ R) {
    __shared__ float red[4][60 * 65];
    int b = blockIdx.x >> 7;
    int rbase = (blockIdx.x & 127) << 4;
    int wv = threadIdx.x >> 6, lane = threadIdx.x & 63;
    int r0 = rbase + wv * 4;
    const float* xp = x + ((size_t)(b * NN + r0)) * NN;

    float acc[4][15];
#pragma unroll
    for (int r = 0; r < 4; r++)
#pragma unroll
        for (int k = 0; k < 15; k++) acc[r][k] = 0.f;

    for (int seg = 0; seg < 8; seg++) {
        int j0 = seg * 256 + lane * 4;
        float4 xv[4];
#pragma unroll
        for (int r = 0; r < 4; r++) xv[r] = *(const float4*)(xp + (size_t)r * NN + j0);
#pragma unroll
        for (int k = 0; k < 15; k++) {
            float4 w4 = *(const float4*)(wl + (size_t)k * NN + j0);
#pragma unroll
            for (int r = 0; r < 4; r++) {
                acc[r][k] = fmaf(xv[r].x, w4.x, acc[r][k]);
                acc[r][k] = fmaf(xv[r].y, w4.y, acc[r][k]);
                acc[r][k] = fmaf(xv[r].z, w4.z, acc[r][k]);
                acc[r][k] = fmaf(xv[r].w, w4.w, acc[r][k]);
            }
        }
    }
#pragma unroll
    for (int r = 0; r < 4; r++)
#pragma unroll
        for (int k = 0; k < 15; k++) red[wv][(r * 15 + k) * 65 + lane] = acc[r][k];
    __syncthreads();
    if (lane < 60) {
        const float* rp = &red[wv][lane * 65];
        float s = 0.f;
#pragma unroll
        for (int j = 0; j < 64; j++) s += rp[j];
        int r = lane / 15, k = lane - r * 15;
        R[(size_t)(b * NN + r0 + r) * 16 + k] = s;
    }
}

// ---------------- k_prep: WF[h][k] = wr[c][h][dw], k=c*3+dw (padded to 16) -------------------
__global__ __launch_bounds__(256) void k_prep(const float* __restrict__ wr,
                                              float* __restrict__ WF) {
    int t = blockIdx.x * 256 + threadIdx.x;  // 128 blocks -> 32768
    if (t >= NN * 16) return;
    int h = t >> 4, k = t & 15;
    float v = 0.f;
    if (k < 15) {
        int c = k / 3, dw = k - c * 3;
        v = wr[c * (NN * 3) + h * 3 + dw];
    }
    WF[t] = v;
}

// ---------------- k_right: CSp[rc][b][k][j] = sum_{h in rc-chunk} x[b,h,j]*WF[h][k] ----------
// grid 256 = 8 b x 8 colchunks(256) x 4 rowchunks(512); block 512 = 8 waves. No global atomics.
__global__ __launch_bounds__(512) void k_right(const float* __restrict__ x,
                                               const float* __restrict__ WF,
                                               float* __restrict__ CSp) {
    __shared__ float wf[512 * 16];   // 32 KB: weights for this row chunk
    __shared__ float CS_l[15 * 256]; // 15 KB: block-level column sums
    int b = blockIdx.x >> 5;
    int rem = blockIdx.x & 31;
    int jc = rem >> 2, rc = rem & 3;
    int j0 = jc * 256, r0 = rc * 512;
    int tid = threadIdx.x;
    int wv = tid >> 6, lane = tid & 63;

    // stage weights (coalesced float4)
#pragma unroll
    for (int s = 0; s < 16; s++) {
        int vi = s * 512 + tid;  // float4 index into 512*16 floats /4 = 2048 vecs
        if (vi < 2048) *(((float4*)wf) + vi) = *(((const float4*)(WF + (size_t)r0 * 16)) + vi);
    }
    // zero block sums
    for (int idx = tid; idx < 15 * 256; idx += 512) CS_l[idx] = 0.f;
    __syncthreads();

    float acc[15][4];
#pragma unroll
    for (int k = 0; k < 15; k++)
#pragma unroll
        for (int e = 0; e < 4; e++) acc[k][e] = 0.f;

    const float* xp = x + ((size_t)b * NN + r0) * NN + j0 + lane * 4;
#pragma unroll 2
    for (int i = 0; i < 64; i++) {
        int rloc = wv + 8 * i;
        float4 xv = *(const float4*)(xp + (size_t)rloc * NN);
        const float* wrow = &wf[rloc * 16];
        float4 w0 = *(const float4*)(wrow);
        float4 w1 = *(const float4*)(wrow + 4);
        float4 w2 = *(const float4*)(wrow + 8);
        float4 w3 = *(const float4*)(wrow + 12);
        float wk[15] = {w0.x, w0.y, w0.z, w0.w, w1.x, w1.y, w1.z, w1.w,
                        w2.x, w2.y, w2.z, w2.w, w3.x, w3.y, w3.z};
#pragma unroll
        for (int k = 0; k < 15; k++) {
            acc[k][0] = fmaf(xv.x, wk[k], acc[k][0]);
            acc[k][1] = fmaf(xv.y, wk[k], acc[k][1]);
            acc[k][2] = fmaf(xv.z, wk[k], acc[k][2]);
            acc[k][3] = fmaf(xv.w, wk[k], acc[k][3]);
        }
    }
    // cross-wave reduce in LDS (8 contenders per address)
    int l4 = lane * 4;
#pragma unroll
    for (int k = 0; k < 15; k++)
#pragma unroll
        for (int e = 0; e < 4; e++) atomicAdd(&CS_l[k * 256 + l4 + e], acc[k][e]);
    __syncthreads();
    // write partial (plain stores, coalesced)
    float* outp = CSp + (((size_t)rc * BB + b) * 16) * NN + j0;
    for (int idx = tid; idx < 15 * 256; idx += 512) {
        int k = idx >> 8, col = idx & 255;
        outp[(size_t)k * NN + col] = CS_l[idx];
    }
}

// ---------------- k_combine: lr[b][ch][i] (ch<5: left_+bl of R; ch>=5: right_+br of CSp) -----
__global__ __launch_bounds__(256) void k_combine(const float* __restrict__ R,
                                                 const float* __restrict__ CSp,
                                                 const float* __restrict__ bl,
                                                 const float* __restrict__ br,
                                                 float* __restrict__ LR) {
    int t = blockIdx.x * 256 + threadIdx.x;
    if (t >= BB * 10 * NN) return;
    int b = t / (10 * NN);
    int rem = t - b * (10 * NN);
    int ch = rem >> 11;
    int i = rem & (NN - 1);
    float v;
    if (ch < 5) {
        v = bl[ch];
#pragma unroll
        for (int dh = 0; dh < 3; dh++) {
            int r = i + dh - 1;
            if (r >= 0 && r < NN) v += R[(size_t)(b * NN + r) * 16 + ch * 3 + dh];
        }
    } else {
        int c = ch - 5;
        v = br[c];
#pragma unroll
        for (int dw = 0; dw < 3; dw++) {
            int j = i + dw - 1;
            if (j >= 0 && j < NN) {
#pragma unroll
                for (int rc = 0; rc < 4; rc++)
                    v += CSp[(((size_t)rc * BB + b) * 16 + c * 3 + dw) * NN + j];
            }
        }
    }
    LR[t] = v;
}

// ---------------- k_chain: 6 conv1d(k=3,pad=1)+relu layers + 1x1 sigmoid head ----------------
// grid 128 = 8 b x 16 chunks(128 cols); halo 6 each side -> ext 140 positions.
__global__ __launch_bounds__(256) void k_chain(const float* __restrict__ LR,
                                               const float* __restrict__ wA, const float* __restrict__ bA,
                                               const float* __restrict__ wB, const float* __restrict__ bB,
                                               const float* __restrict__ wT, const float* __restrict__ bT,
                                               const float* __restrict__ wm, const float* __restrict__ bm,
                                               float* __restrict__ LEFT, float* __restrict__ RIGHT) {
    __shared__ float buf0[10][144], buf1[10][144];
    __shared__ float W[3][10][10][3];
    __shared__ float Bs[3][10];
    __shared__ float Wm[2][10], Bm[2];
    int b = blockIdx.x >> 4;
    int c0 = (blockIdx.x & 15) << 7;
    int tid = threadIdx.x;

    for (int idx = tid; idx < 900; idx += 256) {
        int set = idx / 300, rem = idx - set * 300;
        int o = rem / 30, rem2 = rem - o * 30, c = rem2 / 3, kk = rem2 - c * 3;
        float u;
        if (set == 0) u = wA[o * 30 + c * 3 + kk];
        else if (set == 1) u = wB[o * 30 + c * 3 + kk];
        else u = wT[c * 30 + o * 3 + (2 - kk)];   // wTc[o,c,k] = wT[c,o,2-k]
        W[set][o][c][kk] = u;
    }
    if (tid < 30) {
        float v = (tid < 10) ? bA[tid] : (tid < 20) ? bB[tid - 10] : bT[tid - 20];
        Bs[tid / 10][tid % 10] = v;
    }
    if (tid < 20) Wm[tid / 10][tid % 10] = wm[tid];
    if (tid < 2) Bm[tid] = bm[tid];

    for (int idx = tid; idx < 1400; idx += 256) {
        int ch = idx / 140, p = idx - ch * 140;
        int g = c0 - 6 + p;
        buf0[ch][p] = (g >= 0 && g < NN) ? LR[((size_t)b * 10 + ch) * NN + g] : 0.f;
    }
    __syncthreads();

    float(*in)[144] = buf0;
    float(*out)[144] = buf1;
    for (int layer = 0; layer < 6; layer++) {
        int set = (layer == 0) ? 0 : (layer < 3 ? 1 : 2);
        int lo = layer + 1;  // valid p range [lo, 140-lo)
        for (int idx = tid; idx < 1400; idx += 256) {
            int o = idx / 140, p = idx - o * 140;
            if (p >= lo && p < 140 - lo) {
                float s = Bs[set][o];
#pragma unroll
                for (int c = 0; c < 10; c++) {
                    const float* ip = &in[c][p];
                    s = fmaf(ip[-1], W[set][o][c][0], s);
                    s = fmaf(ip[0], W[set][o][c][1], s);
                    s = fmaf(ip[1], W[set][o][c][2], s);
                }
                s = s > 0.f ? s : 0.f;
                int g = c0 - 6 + p;
                if (g < 0 || g >= NN) s = 0.f;  // reproduce zero padding at global edges
                out[o][p] = s;
            }
        }
        __syncthreads();
        float(*tmp)[144] = in; in = out; out = tmp;
    }
    // 1x1 conv to 2ch + sigmoid; write the 128 owned cols
    {
        int idx = tid;  // 256 = 2 ch x 128 cols
        int o = idx >> 7, pp = idx & 127;
        int p = 6 + pp;
        float s = Bm[o];
#pragma unroll
        for (int c = 0; c < 10; c++) s = fmaf(in[c][p], Wm[o][c], s);
        float sig = 1.f / (1.f + __expf(-s));
        (o ? RIGHT : LEFT)[b * NN + c0 + pp] = sig;
    }
}

// ---------------- k_diag: CUR[d-1][b][i] = exp(x[b,i,i+d]), d in [1,64] ----------------------
// grid 256 = 8 b x 32 rowtiles(64); block 256; LDS transpose for coalesced d-major writes.
__global__ __launch_bounds__(256) void k_diag(const float* __restrict__ x,
                                              float* __restrict__ CUR) {
    __shared__ float T[64][65];
    int b = blockIdx.x >> 5;
    int i0 = (blockIdx.x & 31) << 6;
    int tid = threadIdx.x;
    int rsub = tid >> 3, chunk = tid & 7;
#pragma unroll
    for (int rh = 0; rh < 2; rh++) {
        int rr = rsub + rh * 32;
        int row = i0 + rr;
        const float* xp = x + ((size_t)b * NN + row) * NN;
#pragma unroll
        for (int j = 0; j < 8; j++) {
            int d = chunk * 8 + j + 1;
            int col = row + d;
            float v = 0.f;
            if (col < NN) v = __expf(xp[col]);
            T[rr][d - 1] = v;
        }
    }
    __syncthreads();
    int lane = tid & 63, dgrp = tid >> 6;
#pragma unroll
    for (int sub = 0; sub < 16; sub++) {
        int dm1 = dgrp * 16 + sub;
        CUR[((size_t)dm1 * BB + b) * NN + i0 + lane] = T[lane][dm1];
    }
}

// ---------------- k_mass: P[d][b][i] = log(mass_in/mass_out); atomicAdd psum[d] --------------
// grid 256 = 64 d x 4 q(512 i); block 1024 (2 b-halves x 512 i; each thread 4 batches).
__global__ __launch_bounds__(1024) void k_mass(const float* __restrict__ CUR,
                                               const float* __restrict__ LEFT,
                                               const float* __restrict__ RIGHT,
                                               float* __restrict__ P,
                                               float* __restrict__ psum) {
    __shared__ float wsum[16];
    int dm1 = blockIdx.x >> 2, q = blockIdx.x & 3;
    int d = dm1 + 1;
    int L = (NN - 1) - d;
    int tid = threadIdx.x;
    int b2 = tid >> 9, ii = tid & 511;
    int i = q * 512 + ii;
    float lsum = 0.f;
#pragma unroll
    for (int bs = 0; bs < 4; bs++) {
        int b = b2 + bs * 2;
        float p = 0.f;
        if (i < L) {
            const float* cur = CUR + ((size_t)dm1 * BB + b) * NN;
            const float* lf = LEFT + b * NN;
            const float* rt = RIGHT + b * NN;
            float mi = cur[i + 1] * rt[i + 1] + cur[i] * lf[d + i];
            float mo = rt[i] + lf[d + 1 + i];
            p = __logf(mi / mo);
            lsum += p;
            P[((size_t)dm1 * BB + b) * NN + i] = p;
        }
    }
    for (int off = 32; off; off >>= 1) lsum += __shfl_down(lsum, off);
    int lane = tid & 63, wv = tid >> 6;
    if (lane == 0) wsum[wv] = lsum;
    __syncthreads();
    if (wv == 0) {
        float s = (lane < 16) ? wsum[lane] : 0.f;
        for (int off = 8; off; off >>= 1) s += __shfl_down(s, off);
        if (lane == 0) atomicAdd(&psum[dm1], s);
    }
}

// ---------------- k_out: out = P - psum[d]/(8L), f32 ------------------------------------------
__global__ __launch_bounds__(1024) void k_out(const float* __restrict__ P,
                                              const float* __restrict__ psum,
                                              float* __restrict__ outp) {
    int dm1 = blockIdx.x >> 2, q = blockIdx.x & 3;
    int d = dm1 + 1;
    int L = (NN - 1) - d;
    int tid = threadIdx.x;
    int b2 = tid >> 9, ii = tid & 511;
    int i = q * 512 + ii;
    if (i >= L) return;
    float mean = psum[dm1] / (float)(8 * L);
    size_t off0 = (size_t)dm1 * (NN - 1) - (size_t)dm1 * (dm1 + 1) / 2;
#pragma unroll
    for (int bs = 0; bs < 4; bs++) {
        int b = b2 + bs * 2;
        outp[(size_t)b * TROW + off0 + i] = P[((size_t)dm1 * BB + b) * NN + i] - mean;
    }
}

extern "C" void kernel_launch(void* const* d_in, const int* in_sizes, int n_in,
                              void* d_out, int out_size, void* d_ws, size_t ws_size,
                              hipStream_t stream) {
    const float* x = (const float*)d_in[0];
    const float* wl = (const float*)d_in[1];
    const float* bl = (const float*)d_in[2];
    const float* wr = (const float*)d_in[3];
    const float* br = (const float*)d_in[4];
    const float* wA = (const float*)d_in[5];
    const float* bA = (const float*)d_in[6];
    const float* wB = (const float*)d_in[7];
    const float* bB = (const float*)d_in[8];
    const float* wT = (const float*)d_in[9];
    const float* bT = (const float*)d_in[10];
    const float* wm = (const float*)d_in[11];
    const float* bm = (const float*)d_in[12];

    float* ws = (float*)d_ws;
    float* R    = ws;              // 8*2048*16        = 262144 f
    float* CSp  = ws + 262144;     // 4*8*16*2048      = 1048576 f
    float* WF   = ws + 1310720;    // 2048*16          = 32768 f
    float* LR   = ws + 1343488;    // 8*10*2048        = 163840 f
    float* LEFT = ws + 1507328;    // 8*2048           = 16384 f
    float* RIGHT= ws + 1523712;    // 8*2048           = 16384 f
    float* CUR  = ws + 1540096;    // 64*8*2048        = 1048576 f
    float* P    = ws + 2588672;    // 64*8*2048        = 1048576 f
    float* psum = ws + 3637248;    // 64 f
    // total ~3.64M floats = 14.6 MB

    hipMemsetAsync(psum, 0, 64 * sizeof(float), stream);
    k_left<<<1024, 256, 0, stream>>>(x, wl, R);
    k_prep<<<128, 256, 0, stream>>>(wr, WF);
    k_right<<<256, 512, 0, stream>>>(x, WF, CSp);
    k_combine<<<640, 256, 0, stream>>>(R, CSp, bl, br, LR);
    k_chain<<<128, 256, 0, stream>>>(LR, wA, bA, wB, bB, wT, bT, wm, bm, LEFT, RIGHT);
    k_diag<<<256, 256, 0, stream>>>(x, CUR);
    k_mass<<<256, 1024, 0, stream>>>(CUR, LEFT, RIGHT, P, psum);
    k_out<<<256, 1024, 0, stream>>>(P, psum, (float*)d_out);
}